// Round 10
// baseline (3625.204 us; speedup 1.0000x reference)
//
#include <hip/hip_runtime.h>

#define B_  256
#define T_  512
#define F_  64
#define H_  1024
#define TL_ 64

typedef _Float16 half8 __attribute__((ext_vector_type(8)));
typedef float   floatx4 __attribute__((ext_vector_type(4)));
typedef unsigned long long ull;

#define MFMA(a, b, c) __builtin_amdgcn_mfma_f32_16x16x32_f16(a, b, c, 0, 0, 0)

// ws layout (bytes)
#define WF_E   0UL          // W_hh enc fragments: 3*64*32 chunks * 1024B
#define WF_D   6291456UL    // W_hh dec fragments
#define WF_I   12582912UL   // W_ih enc fragments: 3*64*2 chunks * 1024B
#define HP     12976128UL   // h planes: [2 parity][hi fp16 512KB]
#define PSTR   524288UL     // parity stride
#define PB     15073280UL   // fc partials: [2][64 jg][256 rows] f32
#define BARS   15204352UL   // 16 group lines, 128B apart:
//   line[rg] dword 0      : init-barrier counter (gbar, once)
//   line[rg] dwords 8..23 : per-producer step flags tgs[cb]
// h plane (fragment-major fp16): [rg 16][kb 32][lane 64][16B]; slab 32KB/rg;
// block (rg,cb) owns the contiguous 2KB at rg*32768 + cb*2048.
// NOTE (r10): h stored fp16-only; own-recurrence stays fp32 in hold[].
// NOTE (r20 postmortem of r16/r17/r19): detection must be COALESCED (one
// 16-lane ballot per RTT) and issue must be DISTRIBUTED (8 waves). r16 =
// distributed issue + serial scalar detect (lost); r19 = coalesced detect
// + single-wave issue (lost, +0.75us/step); r17 = both right but fully
// serialized detect -> release-barrier -> issue (champion, 2604us). r20
// fuses them: each wave at A runs its own coalesced ballot loop and
// issues its 2 chunks as soon as THEIR producers are ready — no release
// barrier (3 syncs/step), straggler wait overlaps the other 30 segs'
// fetch. Own chunk = LDS copy from otile (h' of s-1, valid until F).
// Deadlock-free: A-phase waits only on flags published at peers' G of
// step s-1 (never on our current step). Decoder pb-gather: wave 0 polls
// all-16 (pb spans every jg) then gathers, pre-C, decoder only.

// LLC-coherent scalar atomics (sc0 sc1: bypass L1/L2, coherent at IF).
__device__ __forceinline__ void sta8(void* p, ull v) {
  __hip_atomic_store((ull*)p, v, __ATOMIC_RELAXED, __HIP_MEMORY_SCOPE_AGENT);
}
__device__ __forceinline__ void sta4(unsigned* p, unsigned v) {
  __hip_atomic_store(p, v, __ATOMIC_RELAXED, __HIP_MEMORY_SCOPE_AGENT);
}
__device__ __forceinline__ float lda4f(const float* p) {
  return __hip_atomic_load(p, __ATOMIC_RELAXED, __HIP_MEMORY_SCOPE_AGENT);
}
__device__ __forceinline__ unsigned lda4u(const unsigned* p) {
  return __hip_atomic_load(p, __ATOMIC_RELAXED, __HIP_MEMORY_SCOPE_AGENT);
}

// ---------------------------------------------------------------------------
// Setup: W_hh (enc,dec) and W_ih (enc) fp32 -> fp16 MFMA-B fragment layout.
// B-frag 16x16x32: lane L holds B[k=(L>>4)*8+t][n=L&15] ->
// W[g*H + jg*16 + (L&15)][kb*32 + (L>>4)*8 + t].
// Chunk c = (((g*64+jg)*32 + kb)*4 + q)*16 + r ; 16B per chunk-lane.
// ---------------------------------------------------------------------------
__global__ void gru_setup(const float* __restrict__ WhhE,
                          const float* __restrict__ WhhD,
                          const float* __restrict__ WihE,
                          char* __restrict__ ws) {
  int t = blockIdx.x * 256 + threadIdx.x;
  if (t < 512) ((unsigned int*)(ws + BARS))[t] = 0u;   // counters + flags = 0
  const int NW = 3 * 64 * 32 * 4 * 16;
  if (t < 2 * NW) {
    const float* W = (t < NW) ? WhhE : WhhD;
    size_t dst = (t < NW) ? WF_E : WF_D;
    int c = (t < NW) ? t : t - NW;
    int r = c & 15, q = (c >> 4) & 3, kb = (c >> 6) & 31, gj = c >> 11;
    int row = (gj >> 6) * H_ + (gj & 63) * 16 + r;
    const float* src = W + (size_t)row * H_ + kb * 32 + q * 8;
    half8 v;
#pragma unroll
    for (int i = 0; i < 8; ++i) v[i] = (_Float16)src[i];
    *(half8*)(ws + dst + (size_t)c * 16) = v;
  } else if (t < 2 * NW + 3 * 64 * 2 * 4 * 16) {
    int c = t - 2 * NW;
    int r = c & 15, q = (c >> 4) & 3, kc = (c >> 6) & 1, gj = c >> 7;
    int row = (gj >> 6) * H_ + (gj & 63) * 16 + r;
    const float* src = WihE + (size_t)row * F_ + kc * 32 + q * 8;
    half8 v;
#pragma unroll
    for (int i = 0; i < 8; ++i) v[i] = (_Float16)src[i];
    *(half8*)(ws + WF_I + (size_t)c * 16) = v;
  }
}

// Init-only group barrier: 16 blocks (same rg), own cacheline, LLC atomics.
__device__ __forceinline__ void gbar(unsigned int* cnt, unsigned int target) {
  __syncthreads();
  if (threadIdx.x == 0) {
    __hip_atomic_fetch_add(cnt, 1u, __ATOMIC_RELAXED,
                           __HIP_MEMORY_SCOPE_AGENT);
    while (__hip_atomic_load(cnt, __ATOMIC_RELAXED,
                             __HIP_MEMORY_SCOPE_AGENT) < target)
      __builtin_amdgcn_s_sleep(1);
  }
  __syncthreads();
}

// ---------------------------------------------------------------------------
// Main persistent kernel: 256 blocks x 512 thr (8 waves, 1 block/CU) — r17
// structure. Block (rg=bx&15, cb=bx>>4): rows [rg*16,+16), h-cols
// [cb*64,+64). Wave w: jp=w&3 (jg=cb*4+jp), kh=w>>2; bW = 48 chunks.
// Per-step sync: 3 syncthreads (C, E, G) + per-wave fused poll+issue at A.
// ---------------------------------------------------------------------------
__global__ __launch_bounds__(512, 2) void gru_main(
    const float* __restrict__ x,
    const float* __restrict__ bih_e, const float* __restrict__ bhh_e,
    const float* __restrict__ Wih_d,
    const float* __restrict__ bih_d, const float* __restrict__ bhh_d,
    const float* __restrict__ fcW, const float* __restrict__ fcb,
    float* __restrict__ out, char* __restrict__ ws) {

  __shared__ __align__(128) char atile[32768];  // [kb 32][L 64][16B]
  __shared__ float red[4 * 64 * 17];            // kh1 partials [jp][L][17]
  __shared__ __align__(16) char otile[2048];    // h' image (2KB)
  __shared__ float inp_lds[16];

  const int tid = threadIdx.x;
  const int L = tid & 63;
  const int w = tid >> 6;
  const int jp = w & 3;
  const int kh = w >> 2;
  const int bx = blockIdx.x;
  const int rg = bx & 15;
  const int cb = bx >> 4;
  const int r = L & 15;
  const int q = L >> 4;
  const int jg = cb * 4 + jp;
  const int jc = jg * 16 + r;

  unsigned int* line = (unsigned int*)(ws + BARS) + (size_t)rg * 32;
  unsigned int* tgs = line + 8;  // 16 per-producer step flags

  const size_t slab = (size_t)rg * 32768;

  // zero otile (step-0 own-chunk source) + own h'-region of parity 0
  if (tid < 256) {
    *(ull*)(otile + (size_t)tid * 8) = 0ull;
    sta8(ws + HP + slab + (size_t)cb * 2048 + (size_t)tid * 8, 0ull);
  }

  float hold[4] = {0.f, 0.f, 0.f, 0.f};
  const float fcb_s = *fcb;
  const float fcw_l = fcW[jc];

  // one true barrier: all zeros landed before any step-0 staging
  gbar(line, 16);

  for (int phase = 0; phase < 2; ++phase) {
    // register-resident W_hh B-frags for (jg, kh): [gate][kk].
    half8 bW[48];
    {
      const char* wf = ws + (phase ? WF_D : WF_E);
#pragma unroll
      for (int g = 0; g < 3; ++g)
#pragma unroll
        for (int kk = 0; kk < 16; ++kk)
          bW[g * 16 + kk] = *(const half8*)(
              wf + (size_t)((g * 64 + jg) * 32 + kh * 16 + kk) * 1024 +
              (size_t)L * 16);
#pragma unroll
      for (int i = 0; i < 48; ++i) asm volatile("" : "+v"(bW[i]));
    }
    const float* bih = phase ? bih_d : bih_e;
    const float* bhh = phase ? bhh_d : bhh_e;
    const float b_r  = bih[jc]          + bhh[jc];
    const float b_z  = bih[H_ + jc]     + bhh[H_ + jc];
    const float b_in = bih[2 * H_ + jc];
    const float b_hn = bhh[2 * H_ + jc];
    float wd_r = 0.f, wd_z = 0.f, wd_n = 0.f;
    if (phase) {
      wd_r = Wih_d[jc]; wd_z = Wih_d[H_ + jc]; wd_n = Wih_d[2 * H_ + jc];
    }

    const char* wfi = ws + WF_I + (size_t)L * 16;

    const int nsteps = phase ? TL_ : T_;
    for (int d = 0; d < nsteps; ++d) {
      const int s = phase ? T_ + d : d;
      const unsigned gate = (unsigned)s;

      // ---- A: fused per-wave poll+issue. Wave w owns chunks 2w, 2w+1
      //      (segs 4w..4w+3; lane L's 16B at seg base + L*16). One
      //      coalesced 16-lane flag load + ballot per RTT; each chunk's
      //      2KB DMA (aux 17) issues the moment ITS producer is ready.
      //      Own chunk: LDS copy from otile (h' of s-1; zeros at s=0). --
      {
        const char* srcbase = ws + HP + (size_t)(s & 1) * PSTR + slab;
        const int c0 = 2 * w, c1 = 2 * w + 1;
        unsigned need = 0;
        if (c0 != cb) need |= 1u << c0;
        if (c1 != cb) need |= 1u << c1;
        unsigned done = 0;
        while (done != need) {
          unsigned tag = (L < 16) ? lda4u(tgs + L) : 0xFFFFFFFFu;
          ull rdy = __ballot((int)(tag >= gate));
          unsigned newr = ((unsigned)rdy & 0xFFFFu) & need & ~done;
          while (newr) {
            const int j = __builtin_ctz(newr);
            newr &= newr - 1;
#pragma unroll
            for (int t2 = 0; t2 < 2; ++t2) {
              const int seg = j * 2 + t2;
              const char* src =
                  srcbase + (size_t)seg * 1024 + (size_t)L * 16;
              __builtin_amdgcn_global_load_lds(
                  (const __attribute__((address_space(1))) void*)src,
                  (__attribute__((address_space(3))) void*)(atile +
                                                           seg * 1024),
                  16, 0, 17);
            }
            done |= 1u << j;
          }
          if (done != need) __builtin_amdgcn_s_sleep(1);
        }
        if (c0 == cb || c1 == cb) {
#pragma unroll
          for (int t2 = 0; t2 < 2; ++t2)
            *(half8*)(atile + (size_t)(cb * 2 + t2) * 1024 +
                      (size_t)L * 16) =
                *(const half8*)(otile + (size_t)t2 * 1024 + (size_t)L * 16);
        }
      }

      // ---- B: atile-independent work overlaps the DMA flight ----
      floatx4 a0 = {0.f, 0.f, 0.f, 0.f}, a1 = {0.f, 0.f, 0.f, 0.f};
      floatx4 aI = {0.f, 0.f, 0.f, 0.f};
      if (!phase && kh == 1) {
        const float* xp = x + ((size_t)(rg * 16 + r) * T_ + s) * F_ + q * 8;
#pragma unroll
        for (int kc = 0; kc < 2; ++kc) {
          floatx4 x0 = *(const floatx4*)(xp + kc * 32);
          floatx4 x1 = *(const floatx4*)(xp + kc * 32 + 4);
          half8 xa;
#pragma unroll
          for (int i = 0; i < 4; ++i) {
            xa[i] = (_Float16)x0[i];
            xa[4 + i] = (_Float16)x1[i];
          }
          a0 = MFMA(xa, *(const half8*)(wfi +
                   (size_t)((0 * 64 + jg) * 2 + kc) * 1024), a0);
          a1 = MFMA(xa, *(const half8*)(wfi +
                   (size_t)((1 * 64 + jg) * 2 + kc) * 1024), a1);
          aI = MFMA(xa, *(const half8*)(wfi +
                   (size_t)((2 * 64 + jg) * 2 + kc) * 1024), aI);
        }
      }
      // decoder: wave 0 polls ALL 16 flags (pb spans every jg), then
      // gathers pb(d-1). Blocking wait is safe: flags s were published at
      // peers' G of step s-1 — no dependence on our current step.
      if (phase && w == 0) {
        for (;;) {
          unsigned tag = (L < 16) ? lda4u(tgs + L) : 0xFFFFFFFFu;
          if (__all((int)(tag >= gate))) break;
          __builtin_amdgcn_s_sleep(1);
        }
        if (L < 16) {
          float sum = 0.f;
          if (d > 0) {
            const float* pb =
                (const float*)(ws + PB) + (size_t)((d + 1) & 1) * 64 * 256;
            int row = rg * 16 + L;
            float a = fcb_s;
            for (int jj = 0; jj < 64; ++jj) a += lda4f(&pb[jj * 256 + row]);
            sum = a;
            if (cb == 0) out[(size_t)row * TL_ + (d - 1)] = a;
          }
          inp_lds[L] = sum;
        }
      }
      __syncthreads();  // C: drains vmcnt -> atile complete; inp_lds visible

      floatx4 a2 = {0.f, 0.f, 0.f, 0.f};

      // ---- D: h-GEMM, this wave's K-half (stride-1 ds_read_b128);
      //      kh1-enc accumulates on top of the hoisted x-projection ----
#pragma unroll
      for (int kk = 0; kk < 16; ++kk) {
        const int kb = kh * 16 + kk;
        half8 ahi = *(const half8*)(atile + kb * 1024 + L * 16);
        a0 = MFMA(ahi, bW[kk], a0);
        a1 = MFMA(ahi, bW[16 + kk], a1);
        a2 = MFMA(ahi, bW[32 + kk], a2);
      }

      // ---- E: kh1 dumps partials ----
      if (kh == 1) {
        float* rd = &red[(jp * 64 + L) * 17];
#pragma unroll
        for (int i = 0; i < 4; ++i) {
          rd[i] = a0[i];
          rd[4 + i] = a1[i];
          rd[8 + i] = a2[i];
        }
        if (!phase) {
#pragma unroll
          for (int i = 0; i < 4; ++i) rd[12 + i] = aI[i];
        }
      }
      __syncthreads();

      // ---- F: kh0 reduce halves + gate epilogue -> otile; wave jp stores
      //      its own 512B of h' to the global plane (wave-local order) ----
      if (kh == 0) {
        const float* rd = &red[(jp * 64 + L) * 17];
        const size_t tbase = (size_t)(jp >> 1) * 1024 +
                             (size_t)((jp & 1) * 2 + (r >> 3)) * 256 +
                             (size_t)(r & 7) * 2;
        float pv[4];
#pragma unroll
        for (int i = 0; i < 4; ++i) {
          float rpre = a0[i] + rd[i] + b_r;
          float zpre = a1[i] + rd[4 + i] + b_z;
          float hn   = a2[i] + rd[8 + i] + b_hn;
          float inn  = b_in + (phase ? 0.f : rd[12 + i]);
          if (phase) {
            float inp = inp_lds[q * 4 + i];
            rpre += inp * wd_r;
            zpre += inp * wd_z;
            inn  += inp * wd_n;
          }
          float rg_ = 1.f / (1.f + __expf(-rpre));
          float zg = 1.f / (1.f + __expf(-zpre));
          float t2 = __expf(-2.f * (inn + rg_ * hn));
          float ng = 2.f / (1.f + t2) - 1.f;  // tanh, safe at +-inf
          float hnew = (1.f - zg) * ng + zg * hold[i];
          hold[i] = hnew;  // fp32 carry: storage quant never compounds here
          *(_Float16*)(otile + tbase + (size_t)(q * 4 + i) * 16) =
              (_Float16)hnew;
          pv[i] = hnew * fcw_l;
        }
        if (phase) {
#pragma unroll
          for (int i = 0; i < 4; ++i) {
            float v = pv[i];
            v += __shfl_xor(v, 1);
            v += __shfl_xor(v, 2);
            v += __shfl_xor(v, 4);
            v += __shfl_xor(v, 8);
            if (r == 0) {
              float* pb = (float*)(ws + PB) + (size_t)(d & 1) * 64 * 256;
              __hip_atomic_store(&pb[jg * 256 + (rg * 16 + q * 4 + i)], v,
                                 __ATOMIC_RELAXED, __HIP_MEMORY_SCOPE_AGENT);
            }
          }
        }
        // own 512B of h' image -> plane ((s+1)&1), coalesced 8B stores
        ull v8 = *(const ull*)(otile + (size_t)jp * 512 + (size_t)L * 8);
        sta8(ws + HP + (size_t)((s + 1) & 1) * PSTR + slab +
                 (size_t)cb * 2048 + (size_t)jp * 512 + (size_t)L * 8,
             v8);
      }

      // ---- G: drain all waves' stores, then publish flag s+1.
      //      (No release barrier — consumers fuse detect+issue at A.) ----
      __syncthreads();
      if (tid == 0) sta4(tgs + cb, (unsigned)(s + 1));
    }
  }

  // ---- final output column t = TL-1 (one-shot poll: all flags done) ----
  if (cb == 0 && tid < 16) {
    while (lda4u(tgs + tid) < (unsigned)(T_ + TL_))
      __builtin_amdgcn_s_sleep(1);
    const float* pb =
        (const float*)(ws + PB) + (size_t)((TL_ - 1) & 1) * 64 * 256;
    int row = rg * 16 + tid;
    float a = fcb_s;
    for (int jj = 0; jj < 64; ++jj) a += lda4f(&pb[jj * 256 + row]);
    out[(size_t)row * TL_ + (TL_ - 1)] = a;
  }
}

// ---------------------------------------------------------------------------
extern "C" void kernel_launch(void* const* d_in, const int* in_sizes, int n_in,
                              void* d_out, int out_size, void* d_ws,
                              size_t ws_size, hipStream_t stream) {
  const float* x     = (const float*)d_in[0];
  const float* WihE  = (const float*)d_in[1];
  const float* WhhE  = (const float*)d_in[2];
  const float* bihE  = (const float*)d_in[3];
  const float* bhhE  = (const float*)d_in[4];
  const float* WihD  = (const float*)d_in[5];
  const float* WhhD  = (const float*)d_in[6];
  const float* bihD  = (const float*)d_in[7];
  const float* bhhD  = (const float*)d_in[8];
  const float* fcW   = (const float*)d_in[9];
  const float* fcb   = (const float*)d_in[10];
  float* outp = (float*)d_out;
  char* ws = (char*)d_ws;

  gru_setup<<<3168, 256, 0, stream>>>(WhhE, WhhD, WihE, ws);

  gru_main<<<dim3(256), dim3(512), 0, stream>>>(
      x, bihE, bhhE, WihD, bihD, bhhD, fcW, fcb, outp, ws);
}

// Round 11
// 3589.997 us; speedup vs baseline: 1.0098x; 1.0098x over previous
//
#include <hip/hip_runtime.h>

#define B_  256
#define T_  512
#define F_  64
#define H_  1024
#define TL_ 64

typedef _Float16 half8 __attribute__((ext_vector_type(8)));
typedef float   floatx4 __attribute__((ext_vector_type(4)));
typedef unsigned long long ull;

#define MFMA(a, b, c) __builtin_amdgcn_mfma_f32_16x16x32_f16(a, b, c, 0, 0, 0)

// ws layout (bytes)
#define WF_E   0UL          // W_hh enc fragments: 3*64*32 chunks * 1024B
#define WF_D   6291456UL    // W_hh dec fragments
#define WF_I   12582912UL   // W_ih enc fragments: 3*64*2 chunks * 1024B
#define HP     12976128UL   // h planes: [2 parity][hi fp16 512KB]
#define PSTR   524288UL     // parity stride
#define PB     15073280UL   // fc partials: [2][64 jg][256 rows] f32
#define BARS   15204352UL   // 16 group lines, 128B apart:
//   line[rg] dword 0      : init-barrier counter (gbar, once)
//   line[rg] dwords 8..23 : per-producer step flags tgs[cb]
// h plane (fragment-major fp16): [rg 16][kb 32][lane 64][16B]; slab 32KB/rg;
// block (rg,cb) owns the contiguous 2KB at rg*32768 + cb*2048.
// NOTE (r10): h stored fp16-only; own-recurrence stays fp32 in hold[].
// NOTE (r21 postmortem of r16-r20): the sync-design matrix is mapped —
// r16 (distributed serial detect) lost; r19 (central issue) lost; r20
// (8x LLC pollers per block) lost: poll traffic on the flag line scales
// with pollers. Law: exactly ONE coalesced LLC detector per block +
// DISTRIBUTED issue. r17 (champion 2604us) satisfies both but separates
// detect from issue with a release barrier -> zero fetch/straggler
// overlap. r21 = r17 with the release barrier replaced by an LDS MAILBOX:
// wave 0 ballots the 16 flags (one LLC RTT/iter) and publishes the ready
// bitmap incrementally to LDS ((s&0xFFFF)<<16 | bits, monotonic); waves
// 1-7 poll LDS (zero fabric traffic) and issue their chunks' DMAs the
// moment their bits appear -> early producers' fetches overlap straggler
// detection. Own chunk = LDS copy from otile (h' of s-1, stable until F;
// r20-verified). 3 syncthreads/step. Deadlock/WAR induction unchanged
// (A waits only on flags from peers' G of step s-1; verified 3x).

// LLC-coherent scalar atomics (sc0 sc1: bypass L1/L2, coherent at IF).
__device__ __forceinline__ void sta8(void* p, ull v) {
  __hip_atomic_store((ull*)p, v, __ATOMIC_RELAXED, __HIP_MEMORY_SCOPE_AGENT);
}
__device__ __forceinline__ void sta4(unsigned* p, unsigned v) {
  __hip_atomic_store(p, v, __ATOMIC_RELAXED, __HIP_MEMORY_SCOPE_AGENT);
}
__device__ __forceinline__ float lda4f(const float* p) {
  return __hip_atomic_load(p, __ATOMIC_RELAXED, __HIP_MEMORY_SCOPE_AGENT);
}
__device__ __forceinline__ unsigned lda4u(const unsigned* p) {
  return __hip_atomic_load(p, __ATOMIC_RELAXED, __HIP_MEMORY_SCOPE_AGENT);
}
// LDS mailbox ops (workgroup scope -> ds_read/ds_write, no fabric traffic)
__device__ __forceinline__ void mb_st(unsigned* p, unsigned v) {
  __hip_atomic_store(p, v, __ATOMIC_RELAXED, __HIP_MEMORY_SCOPE_WORKGROUP);
}
__device__ __forceinline__ unsigned mb_ld(const unsigned* p) {
  return __hip_atomic_load(p, __ATOMIC_RELAXED, __HIP_MEMORY_SCOPE_WORKGROUP);
}

// ---------------------------------------------------------------------------
// Setup: W_hh (enc,dec) and W_ih (enc) fp32 -> fp16 MFMA-B fragment layout.
// B-frag 16x16x32: lane L holds B[k=(L>>4)*8+t][n=L&15] ->
// W[g*H + jg*16 + (L&15)][kb*32 + (L>>4)*8 + t].
// Chunk c = (((g*64+jg)*32 + kb)*4 + q)*16 + r ; 16B per chunk-lane.
// ---------------------------------------------------------------------------
__global__ void gru_setup(const float* __restrict__ WhhE,
                          const float* __restrict__ WhhD,
                          const float* __restrict__ WihE,
                          char* __restrict__ ws) {
  int t = blockIdx.x * 256 + threadIdx.x;
  if (t < 512) ((unsigned int*)(ws + BARS))[t] = 0u;   // counters + flags = 0
  const int NW = 3 * 64 * 32 * 4 * 16;
  if (t < 2 * NW) {
    const float* W = (t < NW) ? WhhE : WhhD;
    size_t dst = (t < NW) ? WF_E : WF_D;
    int c = (t < NW) ? t : t - NW;
    int r = c & 15, q = (c >> 4) & 3, kb = (c >> 6) & 31, gj = c >> 11;
    int row = (gj >> 6) * H_ + (gj & 63) * 16 + r;
    const float* src = W + (size_t)row * H_ + kb * 32 + q * 8;
    half8 v;
#pragma unroll
    for (int i = 0; i < 8; ++i) v[i] = (_Float16)src[i];
    *(half8*)(ws + dst + (size_t)c * 16) = v;
  } else if (t < 2 * NW + 3 * 64 * 2 * 4 * 16) {
    int c = t - 2 * NW;
    int r = c & 15, q = (c >> 4) & 3, kc = (c >> 6) & 1, gj = c >> 7;
    int row = (gj >> 6) * H_ + (gj & 63) * 16 + r;
    const float* src = WihE + (size_t)row * F_ + kc * 32 + q * 8;
    half8 v;
#pragma unroll
    for (int i = 0; i < 8; ++i) v[i] = (_Float16)src[i];
    *(half8*)(ws + WF_I + (size_t)c * 16) = v;
  }
}

// Init-only group barrier: 16 blocks (same rg), own cacheline, LLC atomics.
__device__ __forceinline__ void gbar(unsigned int* cnt, unsigned int target) {
  __syncthreads();
  if (threadIdx.x == 0) {
    __hip_atomic_fetch_add(cnt, 1u, __ATOMIC_RELAXED,
                           __HIP_MEMORY_SCOPE_AGENT);
    while (__hip_atomic_load(cnt, __ATOMIC_RELAXED,
                             __HIP_MEMORY_SCOPE_AGENT) < target)
      __builtin_amdgcn_s_sleep(1);
  }
  __syncthreads();
}

// ---------------------------------------------------------------------------
// Main persistent kernel: 256 blocks x 512 thr (8 waves, 1 block/CU) — r17
// structure. Block (rg=bx&15, cb=bx>>4): rows [rg*16,+16), h-cols
// [cb*64,+64). Wave w: jp=w&3 (jg=cb*4+jp), kh=w>>2; bW = 48 chunks.
// Per-step sync: 3 syncthreads (C, E, G); wave 0 = sole LLC detector
// publishing to the LDS mailbox; all waves issue their own chunk DMAs.
// ---------------------------------------------------------------------------
__global__ __launch_bounds__(512, 2) void gru_main(
    const float* __restrict__ x,
    const float* __restrict__ bih_e, const float* __restrict__ bhh_e,
    const float* __restrict__ Wih_d,
    const float* __restrict__ bih_d, const float* __restrict__ bhh_d,
    const float* __restrict__ fcW, const float* __restrict__ fcb,
    float* __restrict__ out, char* __restrict__ ws) {

  __shared__ __align__(128) char atile[32768];  // [kb 32][L 64][16B]
  __shared__ float red[4 * 64 * 17];            // kh1 partials [jp][L][17]
  __shared__ __align__(16) char otile[2048];    // h' image (2KB)
  __shared__ float inp_lds[16];
  __shared__ unsigned mbox;                     // (s&0xFFFF)<<16 | readybits

  const int tid = threadIdx.x;
  const int L = tid & 63;
  const int w = tid >> 6;
  const int jp = w & 3;
  const int kh = w >> 2;
  const int bx = blockIdx.x;
  const int rg = bx & 15;
  const int cb = bx >> 4;
  const int r = L & 15;
  const int q = L >> 4;
  const int jg = cb * 4 + jp;
  const int jc = jg * 16 + r;

  unsigned int* line = (unsigned int*)(ws + BARS) + (size_t)rg * 32;
  unsigned int* tgs = line + 8;  // 16 per-producer step flags

  const size_t slab = (size_t)rg * 32768;

  // zero otile (step-0 own-chunk source) + own h'-region of parity 0;
  // init mailbox to an impossible step key (s max 575 < 0xFFFF).
  if (tid == 0) mbox = 0xFFFF0000u;
  if (tid < 256) {
    *(ull*)(otile + (size_t)tid * 8) = 0ull;
    sta8(ws + HP + slab + (size_t)cb * 2048 + (size_t)tid * 8, 0ull);
  }

  float hold[4] = {0.f, 0.f, 0.f, 0.f};
  const float fcb_s = *fcb;
  const float fcw_l = fcW[jc];

  // one true barrier: all zeros landed before any step-0 staging
  gbar(line, 16);

  for (int phase = 0; phase < 2; ++phase) {
    // register-resident W_hh B-frags for (jg, kh): [gate][kk].
    half8 bW[48];
    {
      const char* wf = ws + (phase ? WF_D : WF_E);
#pragma unroll
      for (int g = 0; g < 3; ++g)
#pragma unroll
        for (int kk = 0; kk < 16; ++kk)
          bW[g * 16 + kk] = *(const half8*)(
              wf + (size_t)((g * 64 + jg) * 32 + kh * 16 + kk) * 1024 +
              (size_t)L * 16);
#pragma unroll
      for (int i = 0; i < 48; ++i) asm volatile("" : "+v"(bW[i]));
    }
    const float* bih = phase ? bih_d : bih_e;
    const float* bhh = phase ? bhh_d : bhh_e;
    const float b_r  = bih[jc]          + bhh[jc];
    const float b_z  = bih[H_ + jc]     + bhh[H_ + jc];
    const float b_in = bih[2 * H_ + jc];
    const float b_hn = bhh[2 * H_ + jc];
    float wd_r = 0.f, wd_z = 0.f, wd_n = 0.f;
    if (phase) {
      wd_r = Wih_d[jc]; wd_z = Wih_d[H_ + jc]; wd_n = Wih_d[2 * H_ + jc];
    }

    const char* wfi = ws + WF_I + (size_t)L * 16;

    const int nsteps = phase ? TL_ : T_;
    for (int d = 0; d < nsteps; ++d) {
      const int s = phase ? T_ + d : d;
      const unsigned gate = (unsigned)s;
      const unsigned skey = (unsigned)(s & 0xFFFF) << 16;
      const char* srcbase = ws + HP + (size_t)(s & 1) * PSTR + slab;

      // ---- A0: own chunk first — LDS copy from otile (h' of s-1;
      //      zeros at s=0). Done by the wave that owns chunk cb. ----
      if (w == (cb >> 1)) {
#pragma unroll
        for (int t2 = 0; t2 < 2; ++t2)
          *(half8*)(atile + (size_t)(cb * 2 + t2) * 1024 + (size_t)L * 16) =
              *(const half8*)(otile + (size_t)t2 * 1024 + (size_t)L * 16);
      }

      // ---- A: detection + distributed ASAP issue.
      //      Wave 0: sole LLC poller — one coalesced 16-lane load +
      //      ballot per RTT; publishes bitmap to the LDS mailbox as it
      //      grows; issues its own chunks when ready. Waves 1-7: poll
      //      the mailbox (ds_read, no fabric traffic) and issue each
      //      chunk's 2KB DMA (aux 17) the moment its bit appears. ----
      if (w == 0) {
        unsigned done = 0, issued = 0;
        const unsigned mine = 0x3u & ~(1u << cb);
        for (;;) {
          unsigned tag = (L < 16) ? lda4u(tgs + L) : 0xFFFFFFFFu;
          ull rdy = __ballot((int)(tag >= gate));
          unsigned nr = (unsigned)rdy & 0xFFFFu;
          if (nr != done) {
            done = nr;
            if (L == 0) mb_st(&mbox, skey | done);
            unsigned newi = done & mine & ~issued;
            while (newi) {
              const int j = __builtin_ctz(newi);
              newi &= newi - 1;
#pragma unroll
              for (int t2 = 0; t2 < 2; ++t2) {
                const int seg = j * 2 + t2;
                const char* src =
                    srcbase + (size_t)seg * 1024 + (size_t)L * 16;
                __builtin_amdgcn_global_load_lds(
                    (const __attribute__((address_space(1))) void*)src,
                    (__attribute__((address_space(3))) void*)(atile +
                                                             seg * 1024),
                    16, 0, 17);
              }
              issued |= 1u << j;
            }
          }
          if (done == 0xFFFFu) break;
          __builtin_amdgcn_s_sleep(1);
        }
        // decoder scalar input: all flags >= s implies pb(d-1) drained.
        if (phase && L < 16) {
          float sum = 0.f;
          if (d > 0) {
            const float* pb =
                (const float*)(ws + PB) + (size_t)((d + 1) & 1) * 64 * 256;
            int row = rg * 16 + L;
            float a = fcb_s;
            for (int jj = 0; jj < 64; ++jj) a += lda4f(&pb[jj * 256 + row]);
            sum = a;
            if (cb == 0) out[(size_t)row * TL_ + (d - 1)] = a;
          }
          inp_lds[L] = sum;
        }
      } else {
        unsigned mine = 0;
        const int c0 = 2 * w, c1 = 2 * w + 1;
        if (c0 != cb) mine |= 1u << c0;
        if (c1 != cb) mine |= 1u << c1;
        unsigned issued = 0;
        while (issued != mine) {
          unsigned m = mb_ld(&mbox);
          if ((m & 0xFFFF0000u) == skey) {
            unsigned avail = (m & 0xFFFFu) & mine & ~issued;
            while (avail) {
              const int j = __builtin_ctz(avail);
              avail &= avail - 1;
#pragma unroll
              for (int t2 = 0; t2 < 2; ++t2) {
                const int seg = j * 2 + t2;
                const char* src =
                    srcbase + (size_t)seg * 1024 + (size_t)L * 16;
                __builtin_amdgcn_global_load_lds(
                    (const __attribute__((address_space(1))) void*)src,
                    (__attribute__((address_space(3))) void*)(atile +
                                                             seg * 1024),
                    16, 0, 17);
              }
              issued |= 1u << j;
            }
          }
          if (issued != mine) __builtin_amdgcn_s_sleep(1);
        }
      }

      // ---- B: atile-independent x-projection overlaps the DMA flight ----
      floatx4 a0 = {0.f, 0.f, 0.f, 0.f}, a1 = {0.f, 0.f, 0.f, 0.f};
      floatx4 aI = {0.f, 0.f, 0.f, 0.f};
      if (!phase && kh == 1) {
        const float* xp = x + ((size_t)(rg * 16 + r) * T_ + s) * F_ + q * 8;
#pragma unroll
        for (int kc = 0; kc < 2; ++kc) {
          floatx4 x0 = *(const floatx4*)(xp + kc * 32);
          floatx4 x1 = *(const floatx4*)(xp + kc * 32 + 4);
          half8 xa;
#pragma unroll
          for (int i = 0; i < 4; ++i) {
            xa[i] = (_Float16)x0[i];
            xa[4 + i] = (_Float16)x1[i];
          }
          a0 = MFMA(xa, *(const half8*)(wfi +
                   (size_t)((0 * 64 + jg) * 2 + kc) * 1024), a0);
          a1 = MFMA(xa, *(const half8*)(wfi +
                   (size_t)((1 * 64 + jg) * 2 + kc) * 1024), a1);
          aI = MFMA(xa, *(const half8*)(wfi +
                   (size_t)((2 * 64 + jg) * 2 + kc) * 1024), aI);
        }
      }
      __syncthreads();  // C: drains vmcnt -> atile complete; inp_lds visible

      floatx4 a2 = {0.f, 0.f, 0.f, 0.f};

      // ---- D: h-GEMM, this wave's K-half (stride-1 ds_read_b128);
      //      kh1-enc accumulates on top of the hoisted x-projection ----
#pragma unroll
      for (int kk = 0; kk < 16; ++kk) {
        const int kb = kh * 16 + kk;
        half8 ahi = *(const half8*)(atile + kb * 1024 + L * 16);
        a0 = MFMA(ahi, bW[kk], a0);
        a1 = MFMA(ahi, bW[16 + kk], a1);
        a2 = MFMA(ahi, bW[32 + kk], a2);
      }

      // ---- E: kh1 dumps partials ----
      if (kh == 1) {
        float* rd = &red[(jp * 64 + L) * 17];
#pragma unroll
        for (int i = 0; i < 4; ++i) {
          rd[i] = a0[i];
          rd[4 + i] = a1[i];
          rd[8 + i] = a2[i];
        }
        if (!phase) {
#pragma unroll
          for (int i = 0; i < 4; ++i) rd[12 + i] = aI[i];
        }
      }
      __syncthreads();

      // ---- F: kh0 reduce halves + gate epilogue -> otile; wave jp stores
      //      its own 512B of h' to the global plane (wave-local order) ----
      if (kh == 0) {
        const float* rd = &red[(jp * 64 + L) * 17];
        const size_t tbase = (size_t)(jp >> 1) * 1024 +
                             (size_t)((jp & 1) * 2 + (r >> 3)) * 256 +
                             (size_t)(r & 7) * 2;
        float pv[4];
#pragma unroll
        for (int i = 0; i < 4; ++i) {
          float rpre = a0[i] + rd[i] + b_r;
          float zpre = a1[i] + rd[4 + i] + b_z;
          float hn   = a2[i] + rd[8 + i] + b_hn;
          float inn  = b_in + (phase ? 0.f : rd[12 + i]);
          if (phase) {
            float inp = inp_lds[q * 4 + i];
            rpre += inp * wd_r;
            zpre += inp * wd_z;
            inn  += inp * wd_n;
          }
          float rg_ = 1.f / (1.f + __expf(-rpre));
          float zg = 1.f / (1.f + __expf(-zpre));
          float t2 = __expf(-2.f * (inn + rg_ * hn));
          float ng = 2.f / (1.f + t2) - 1.f;  // tanh, safe at +-inf
          float hnew = (1.f - zg) * ng + zg * hold[i];
          hold[i] = hnew;  // fp32 carry: storage quant never compounds here
          *(_Float16*)(otile + tbase + (size_t)(q * 4 + i) * 16) =
              (_Float16)hnew;
          pv[i] = hnew * fcw_l;
        }
        if (phase) {
#pragma unroll
          for (int i = 0; i < 4; ++i) {
            float v = pv[i];
            v += __shfl_xor(v, 1);
            v += __shfl_xor(v, 2);
            v += __shfl_xor(v, 4);
            v += __shfl_xor(v, 8);
            if (r == 0) {
              float* pb = (float*)(ws + PB) + (size_t)(d & 1) * 64 * 256;
              __hip_atomic_store(&pb[jg * 256 + (rg * 16 + q * 4 + i)], v,
                                 __ATOMIC_RELAXED, __HIP_MEMORY_SCOPE_AGENT);
            }
          }
        }
        // own 512B of h' image -> plane ((s+1)&1), coalesced 8B stores
        ull v8 = *(const ull*)(otile + (size_t)jp * 512 + (size_t)L * 8);
        sta8(ws + HP + (size_t)((s + 1) & 1) * PSTR + slab +
                 (size_t)cb * 2048 + (size_t)jp * 512 + (size_t)L * 8,
             v8);
      }

      // ---- G: drain all waves' stores, then publish flag s+1.
      //      (No release barrier — consumers poll mailbox in next A.) ----
      __syncthreads();
      if (tid == 0) sta4(tgs + cb, (unsigned)(s + 1));
    }
  }

  // ---- final output column t = TL-1 (one-shot poll: all flags done) ----
  if (cb == 0 && tid < 16) {
    while (lda4u(tgs + tid) < (unsigned)(T_ + TL_))
      __builtin_amdgcn_s_sleep(1);
    const float* pb =
        (const float*)(ws + PB) + (size_t)((TL_ - 1) & 1) * 64 * 256;
    int row = rg * 16 + tid;
    float a = fcb_s;
    for (int jj = 0; jj < 64; ++jj) a += lda4f(&pb[jj * 256 + row]);
    out[(size_t)row * TL_ + (TL_ - 1)] = a;
  }
}

// ---------------------------------------------------------------------------
extern "C" void kernel_launch(void* const* d_in, const int* in_sizes, int n_in,
                              void* d_out, int out_size, void* d_ws,
                              size_t ws_size, hipStream_t stream) {
  const float* x     = (const float*)d_in[0];
  const float* WihE  = (const float*)d_in[1];
  const float* WhhE  = (const float*)d_in[2];
  const float* bihE  = (const float*)d_in[3];
  const float* bhhE  = (const float*)d_in[4];
  const float* WihD  = (const float*)d_in[5];
  const float* WhhD  = (const float*)d_in[6];
  const float* bihD  = (const float*)d_in[7];
  const float* bhhD  = (const float*)d_in[8];
  const float* fcW   = (const float*)d_in[9];
  const float* fcb   = (const float*)d_in[10];
  float* outp = (float*)d_out;
  char* ws = (char*)d_ws;

  gru_setup<<<3168, 256, 0, stream>>>(WhhE, WhhD, WihE, ws);

  gru_main<<<dim3(256), dim3(512), 0, stream>>>(
      x, bihE, bhhE, WihD, bihD, bhhD, fcW, fcb, outp, ws);
}

// Round 12
// 2610.414 us; speedup vs baseline: 1.3887x; 1.3753x over previous
//
#include <hip/hip_runtime.h>

#define B_  256
#define T_  512
#define F_  64
#define H_  1024
#define TL_ 64

typedef _Float16 half8 __attribute__((ext_vector_type(8)));
typedef float   floatx4 __attribute__((ext_vector_type(4)));
typedef unsigned long long ull;

#define MFMA(a, b, c) __builtin_amdgcn_mfma_f32_16x16x32_f16(a, b, c, 0, 0, 0)

// ws layout (bytes)
#define WF_E   0UL          // W_hh enc fragments: 3*64*32 chunks * 1024B
#define WF_D   6291456UL    // W_hh dec fragments
#define WF_I   12582912UL   // W_ih enc fragments: 3*64*2 chunks * 1024B
#define HP     12976128UL   // h planes: [2 parity][hi fp16 512KB]
#define PSTR   524288UL     // parity stride
#define PB     15073280UL   // fc partials: [2][64 jg][256 rows] f32
#define BARS   15204352UL   // 16 group lines, 128B apart:
//   line[rg] dword 0      : init-barrier counter (gbar, used once)
//   line[rg] dwords 8..23 : per-producer step flags  tgs[cb]
// h plane (fragment-major fp16): [rg 16][kb 32][lane 64][16B]; slab 32KB/rg;
// block (rg,cb) owns the contiguous 2KB at rg*32768 + cb*2048.
// NOTE (r10): h stored fp16-only; own-recurrence stays fp32 in hold[].
// NOTE (r22 FINAL, postmortem of r11-r21): this is the byte-exact r17
// champion (2604us). The full design space around it was measured:
//  - XCD-local data plane: correct but slower via aux=1 DMA (r13,
//    +2.2us/step); asm-sc0 signaling hangs (r11, r18). Closed.
//  - x-proj hoist across the GEMM at 128 VGPR: spills, +304MB scratch
//    writes (r14). Closed.
//  - 2 groups/CU or any re-partition: staged bytes scale with block
//    count, step time follows (r15, 1.9x). Decomposition is optimal.
//  - Sync restructures: distributed serial detect (r16), centralized
//    issue (r19), 8x LLC pollers (r20), LDS-mailbox release (r21) —
//    all lose ~0.7-1us/step to r17's uniform barrier-separated phases.
//    Blocks run in soft lockstep (slack=1 step): flags for s+1 arrive
//    when we finish G(s), so there is no skew window to overlap, and
//    divergent staging code costs VALU every step.
// Step budget: ~1.4us compute + ~3 serialized LLC RTTs (h'-drain ->
// flag publish+coalesced detect -> 32KB staging fetch). 576 sequential
// all-to-all exchange rounds = a latency floor, not a counter roofline
// (MfmaUtil 15%, HBM 3%). Law: ONE coalesced LLC detector per block +
// distributed issue + uniform phases.

// LLC-coherent scalar atomics (sc0 sc1: bypass L1/L2, coherent at IF).
__device__ __forceinline__ void sta8(void* p, ull v) {
  __hip_atomic_store((ull*)p, v, __ATOMIC_RELAXED, __HIP_MEMORY_SCOPE_AGENT);
}
__device__ __forceinline__ void sta4(unsigned* p, unsigned v) {
  __hip_atomic_store(p, v, __ATOMIC_RELAXED, __HIP_MEMORY_SCOPE_AGENT);
}
__device__ __forceinline__ float lda4f(const float* p) {
  return __hip_atomic_load(p, __ATOMIC_RELAXED, __HIP_MEMORY_SCOPE_AGENT);
}
__device__ __forceinline__ unsigned lda4u(const unsigned* p) {
  return __hip_atomic_load(p, __ATOMIC_RELAXED, __HIP_MEMORY_SCOPE_AGENT);
}

// ---------------------------------------------------------------------------
// Setup: W_hh (enc,dec) and W_ih (enc) fp32 -> fp16 MFMA-B fragment layout.
// B-frag 16x16x32: lane L holds B[k=(L>>4)*8+t][n=L&15] ->
// W[g*H + jg*16 + (L&15)][kb*32 + (L>>4)*8 + t].
// Chunk c = (((g*64+jg)*32 + kb)*4 + q)*16 + r ; 16B per chunk-lane.
// ---------------------------------------------------------------------------
__global__ void gru_setup(const float* __restrict__ WhhE,
                          const float* __restrict__ WhhD,
                          const float* __restrict__ WihE,
                          char* __restrict__ ws) {
  int t = blockIdx.x * 256 + threadIdx.x;
  if (t < 512) ((unsigned int*)(ws + BARS))[t] = 0u;   // counters + flags = 0
  const int NW = 3 * 64 * 32 * 4 * 16;
  if (t < 2 * NW) {
    const float* W = (t < NW) ? WhhE : WhhD;
    size_t dst = (t < NW) ? WF_E : WF_D;
    int c = (t < NW) ? t : t - NW;
    int r = c & 15, q = (c >> 4) & 3, kb = (c >> 6) & 31, gj = c >> 11;
    int row = (gj >> 6) * H_ + (gj & 63) * 16 + r;
    const float* src = W + (size_t)row * H_ + kb * 32 + q * 8;
    half8 v;
#pragma unroll
    for (int i = 0; i < 8; ++i) v[i] = (_Float16)src[i];
    *(half8*)(ws + dst + (size_t)c * 16) = v;
  } else if (t < 2 * NW + 3 * 64 * 2 * 4 * 16) {
    int c = t - 2 * NW;
    int r = c & 15, q = (c >> 4) & 3, kc = (c >> 6) & 1, gj = c >> 7;
    int row = (gj >> 6) * H_ + (gj & 63) * 16 + r;
    const float* src = WihE + (size_t)row * F_ + kc * 32 + q * 8;
    half8 v;
#pragma unroll
    for (int i = 0; i < 8; ++i) v[i] = (_Float16)src[i];
    *(half8*)(ws + WF_I + (size_t)c * 16) = v;
  }
}

// Init-only group barrier: 16 blocks (same rg), own cacheline, LLC atomics.
__device__ __forceinline__ void gbar(unsigned int* cnt, unsigned int target) {
  __syncthreads();
  if (threadIdx.x == 0) {
    __hip_atomic_fetch_add(cnt, 1u, __ATOMIC_RELAXED,
                           __HIP_MEMORY_SCOPE_AGENT);
    while (__hip_atomic_load(cnt, __ATOMIC_RELAXED,
                             __HIP_MEMORY_SCOPE_AGENT) < target)
      __builtin_amdgcn_s_sleep(1);
  }
  __syncthreads();
}

// ---------------------------------------------------------------------------
// Main persistent kernel: 256 blocks x 512 thr (8 waves, 1 block/CU).
// Block (rg=bx&15, cb=bx>>4): rows [rg*16,+16), h-cols [cb*64,+64).
// Wave w: jp=w&3 (jg=cb*4+jp), kh=w>>2; bW = 48 chunks.
// Per-step sync: flag stores + one 16-lane coalesced poll (wave 0) +
// syncthreads release. 4 syncthreads/step total.
// ---------------------------------------------------------------------------
__global__ __launch_bounds__(512, 2) void gru_main(
    const float* __restrict__ x,
    const float* __restrict__ bih_e, const float* __restrict__ bhh_e,
    const float* __restrict__ Wih_d,
    const float* __restrict__ bih_d, const float* __restrict__ bhh_d,
    const float* __restrict__ fcW, const float* __restrict__ fcb,
    float* __restrict__ out, char* __restrict__ ws) {

  __shared__ __align__(128) char atile[32768];  // [kb 32][L 64][16B]
  __shared__ float red[4 * 64 * 17];            // kh1 partials [jp][L][17]
  __shared__ __align__(16) char otile[2048];    // h' image (2KB)
  __shared__ float inp_lds[16];

  const int tid = threadIdx.x;
  const int L = tid & 63;
  const int w = tid >> 6;
  const int jp = w & 3;
  const int kh = w >> 2;
  const int bx = blockIdx.x;
  const int rg = bx & 15;
  const int cb = bx >> 4;
  const int r = L & 15;
  const int q = L >> 4;
  const int jg = cb * 4 + jp;
  const int jc = jg * 16 + r;

  unsigned int* line = (unsigned int*)(ws + BARS) + (size_t)rg * 32;
  unsigned int* tgs = line + 8;  // 16 per-producer step flags

  const size_t slab = (size_t)rg * 32768;

  // zero own h'-region of parity 0 (2KB/block)
  if (tid < 256) {
    sta8(ws + HP + slab + (size_t)cb * 2048 + (size_t)tid * 8, 0ull);
  }

  float hold[4] = {0.f, 0.f, 0.f, 0.f};
  const float fcb_s = *fcb;
  const float fcw_l = fcW[jc];

  // one true barrier: all zeros landed before any step-0 staging
  gbar(line, 16);

  for (int phase = 0; phase < 2; ++phase) {
    // register-resident W_hh B-frags for (jg, kh): [gate][kk].
    half8 bW[48];
    {
      const char* wf = ws + (phase ? WF_D : WF_E);
#pragma unroll
      for (int g = 0; g < 3; ++g)
#pragma unroll
        for (int kk = 0; kk < 16; ++kk)
          bW[g * 16 + kk] = *(const half8*)(
              wf + (size_t)((g * 64 + jg) * 32 + kh * 16 + kk) * 1024 +
              (size_t)L * 16);
#pragma unroll
      for (int i = 0; i < 48; ++i) asm volatile("" : "+v"(bW[i]));
    }
    const float* bih = phase ? bih_d : bih_e;
    const float* bhh = phase ? bhh_d : bhh_e;
    const float b_r  = bih[jc]          + bhh[jc];
    const float b_z  = bih[H_ + jc]     + bhh[H_ + jc];
    const float b_in = bih[2 * H_ + jc];
    const float b_hn = bhh[2 * H_ + jc];
    float wd_r = 0.f, wd_z = 0.f, wd_n = 0.f;
    if (phase) {
      wd_r = Wih_d[jc]; wd_z = Wih_d[H_ + jc]; wd_n = Wih_d[2 * H_ + jc];
    }

    const char* wfi = ws + WF_I + (size_t)L * 16;

    const int nsteps = phase ? TL_ : T_;
    for (int d = 0; d < nsteps; ++d) {
      const int s = phase ? T_ + d : d;
      const unsigned tnext = (unsigned)(s + 1);

      // ---- A: stage A slab (32KB) via async global->LDS DMA, aux 17
      //      (sc0|sc1, LLC-coherent). 32 segs of 1KB; wave w takes segs
      //      w*4..w*4+3; lane L's 16B lands at seg base + L*16. ----
      {
        const char* srcbase = ws + HP + (size_t)(s & 1) * PSTR + slab;
#pragma unroll
        for (int c = 0; c < 4; ++c) {
          const int seg = w * 4 + c;  // 0..31
          const char* src = srcbase + (size_t)seg * 1024 + (size_t)L * 16;
          __builtin_amdgcn_global_load_lds(
              (const __attribute__((address_space(1))) void*)src,
              (__attribute__((address_space(3))) void*)(atile + seg * 1024),
              16, 0, 17);
        }
      }

      // ---- B: atile-independent work overlaps the DMA latency ----
      // enc kh1: x-projection into a0,a1,aI (x + W_ih only)
      floatx4 a0 = {0.f, 0.f, 0.f, 0.f}, a1 = {0.f, 0.f, 0.f, 0.f};
      floatx4 aI = {0.f, 0.f, 0.f, 0.f};
      if (!phase && kh == 1) {
        const float* xp = x + ((size_t)(rg * 16 + r) * T_ + s) * F_ + q * 8;
#pragma unroll
        for (int kc = 0; kc < 2; ++kc) {
          floatx4 x0 = *(const floatx4*)(xp + kc * 32);
          floatx4 x1 = *(const floatx4*)(xp + kc * 32 + 4);
          half8 xa;
#pragma unroll
          for (int i = 0; i < 4; ++i) {
            xa[i] = (_Float16)x0[i];
            xa[4 + i] = (_Float16)x1[i];
          }
          a0 = MFMA(xa, *(const half8*)(wfi +
                   (size_t)((0 * 64 + jg) * 2 + kc) * 1024), a0);
          a1 = MFMA(xa, *(const half8*)(wfi +
                   (size_t)((1 * 64 + jg) * 2 + kc) * 1024), a1);
          aI = MFMA(xa, *(const half8*)(wfi +
                   (size_t)((2 * 64 + jg) * 2 + kc) * 1024), aI);
        }
      }
      // dec: scalar input gather (pb(d-1) guaranteed by the step-(s-1)
      // barrier: all flags >= s implies all pb stores drained)
      if (phase && tid < 16) {
        float sum = 0.f;
        if (d > 0) {
          const float* pb =
              (const float*)(ws + PB) + (size_t)((d + 1) & 1) * 64 * 256;
          int row = rg * 16 + tid;
          float a = fcb_s;
          for (int jj = 0; jj < 64; ++jj) a += lda4f(&pb[jj * 256 + row]);
          sum = a;
          if (cb == 0) out[(size_t)row * TL_ + (d - 1)] = a;
        }
        inp_lds[tid] = sum;
      }
      __syncthreads();  // C: drains vmcnt -> staging DMA complete

      floatx4 a2 = {0.f, 0.f, 0.f, 0.f};

      // ---- D: h-GEMM, this wave's K-half (stride-1 ds_read_b128);
      //      kh1-enc accumulates on top of the hoisted x-projection ----
#pragma unroll
      for (int kk = 0; kk < 16; ++kk) {
        const int kb = kh * 16 + kk;
        half8 ahi = *(const half8*)(atile + kb * 1024 + L * 16);
        a0 = MFMA(ahi, bW[kk], a0);
        a1 = MFMA(ahi, bW[16 + kk], a1);
        a2 = MFMA(ahi, bW[32 + kk], a2);
      }

      // ---- E: kh1 dumps partials ----
      if (kh == 1) {
        float* rd = &red[(jp * 64 + L) * 17];
#pragma unroll
        for (int i = 0; i < 4; ++i) {
          rd[i] = a0[i];
          rd[4 + i] = a1[i];
          rd[8 + i] = a2[i];
        }
        if (!phase) {
#pragma unroll
          for (int i = 0; i < 4; ++i) rd[12 + i] = aI[i];
        }
      }
      __syncthreads();

      // ---- F: kh0 reduce halves + gate epilogue -> otile; then wave jp
      //      stores ITS OWN otile 512B [jp*512,+512) to the global plane
      //      (wave-local lgkmcnt ordering; no cross-wave sync needed) ----
      if (kh == 0) {
        const float* rd = &red[(jp * 64 + L) * 17];
        const size_t tbase = (size_t)(jp >> 1) * 1024 +
                             (size_t)((jp & 1) * 2 + (r >> 3)) * 256 +
                             (size_t)(r & 7) * 2;
        float pv[4];
#pragma unroll
        for (int i = 0; i < 4; ++i) {
          float rpre = a0[i] + rd[i] + b_r;
          float zpre = a1[i] + rd[4 + i] + b_z;
          float hn   = a2[i] + rd[8 + i] + b_hn;
          float inn  = b_in + (phase ? 0.f : rd[12 + i]);
          if (phase) {
            float inp = inp_lds[q * 4 + i];
            rpre += inp * wd_r;
            zpre += inp * wd_z;
            inn  += inp * wd_n;
          }
          float rg_ = 1.f / (1.f + __expf(-rpre));
          float zg = 1.f / (1.f + __expf(-zpre));
          float t2 = __expf(-2.f * (inn + rg_ * hn));
          float ng = 2.f / (1.f + t2) - 1.f;  // tanh, safe at +-inf
          float hnew = (1.f - zg) * ng + zg * hold[i];
          hold[i] = hnew;  // fp32 carry: storage quant never compounds here
          *(_Float16*)(otile + tbase + (size_t)(q * 4 + i) * 16) =
              (_Float16)hnew;
          pv[i] = hnew * fcw_l;
        }
        if (phase) {
#pragma unroll
          for (int i = 0; i < 4; ++i) {
            float v = pv[i];
            v += __shfl_xor(v, 1);
            v += __shfl_xor(v, 2);
            v += __shfl_xor(v, 4);
            v += __shfl_xor(v, 8);
            if (r == 0) {
              float* pb = (float*)(ws + PB) + (size_t)(d & 1) * 64 * 256;
              __hip_atomic_store(&pb[jg * 256 + (rg * 16 + q * 4 + i)], v,
                                 __ATOMIC_RELAXED, __HIP_MEMORY_SCOPE_AGENT);
            }
          }
        }
        // own 512B of h' image -> plane ((s+1)&1), coalesced 8B stores
        ull v8 = *(const ull*)(otile + (size_t)jp * 512 + (size_t)L * 8);
        sta8(ws + HP + (size_t)((s + 1) & 1) * PSTR + slab +
                 (size_t)cb * 2048 + (size_t)jp * 512 + (size_t)L * 8,
             v8);
      }

      // ---- G/H/I/J: drain -> publish flag -> coalesced poll -> release --
      __syncthreads();  // every wave drained its vmcnt before s_barrier
      if (tid == 0) sta4(tgs + cb, tnext);
      if (w == 0) {
        for (;;) {
          unsigned tag = (L < 16) ? lda4u(tgs + L) : tnext;
          if (__all((int)(tag >= tnext))) break;
          __builtin_amdgcn_s_sleep(1);
        }
      }
      __syncthreads();
    }
  }

  // ---- final output column t = TL-1 (all flags = T_+TL_ after the loop) --
  if (cb == 0 && tid < 16) {
    const float* pb =
        (const float*)(ws + PB) + (size_t)((TL_ - 1) & 1) * 64 * 256;
    int row = rg * 16 + tid;
    float a = fcb_s;
    for (int jj = 0; jj < 64; ++jj) a += lda4f(&pb[jj * 256 + row]);
    out[(size_t)row * TL_ + (TL_ - 1)] = a;
  }
}

// ---------------------------------------------------------------------------
extern "C" void kernel_launch(void* const* d_in, const int* in_sizes, int n_in,
                              void* d_out, int out_size, void* d_ws,
                              size_t ws_size, hipStream_t stream) {
  const float* x     = (const float*)d_in[0];
  const float* WihE  = (const float*)d_in[1];
  const float* WhhE  = (const float*)d_in[2];
  const float* bihE  = (const float*)d_in[3];
  const float* bhhE  = (const float*)d_in[4];
  const float* WihD  = (const float*)d_in[5];
  const float* WhhD  = (const float*)d_in[6];
  const float* bihD  = (const float*)d_in[7];
  const float* bhhD  = (const float*)d_in[8];
  const float* fcW   = (const float*)d_in[9];
  const float* fcb   = (const float*)d_in[10];
  float* outp = (float*)d_out;
  char* ws = (char*)d_ws;

  gru_setup<<<3168, 256, 0, stream>>>(WhhE, WhhD, WihE, ws);

  gru_main<<<dim3(256), dim3(512), 0, stream>>>(
      x, bihE, bhhE, WihD, bihD, bhhD, fcW, fcb, outp, ws);
}